// Round 17
// baseline (12931.421 us; speedup 1.0000x reference)
//
#include <hip/hip_runtime.h>
#include <stdint.h>

#define B_  64
#define S_  512
#define E_  256
#define H_  512

typedef float  f32x4  __attribute__((ext_vector_type(4)));
typedef __bf16 bf16x8 __attribute__((ext_vector_type(8)));
typedef unsigned long long u64t;

__device__ __forceinline__ unsigned short f2b(float f) {
  uint32_t u = __builtin_bit_cast(uint32_t, f);
  uint32_t r = (u + 0x7FFFu + ((u >> 16) & 1u)) >> 16;
  return (unsigned short)r;
}
__device__ __forceinline__ float b2f(unsigned short s) {
  uint32_t u = ((uint32_t)s) << 16;
  return __builtin_bit_cast(float, u);
}
__device__ __forceinline__ bf16x8 ld_bf8(const unsigned short* p) {
  uint4 v = *reinterpret_cast<const uint4*>(p);
  return __builtin_bit_cast(bf16x8, v);
}

// ---------------- convert emb + W_ih to bf16 ----------------
__global__ void convert_kernel(const float* __restrict__ emb,
                               const float* __restrict__ wih,
                               unsigned short* __restrict__ emb_b,
                               unsigned short* __restrict__ wih_b) {
  const int64_t EMB_N = (int64_t)32000 * 256;
  const int64_t TOT8  = (EMB_N + (int64_t)1536 * 256) / 8;
  for (int64_t i8 = (int64_t)blockIdx.x * blockDim.x + threadIdx.x; i8 < TOT8;
       i8 += (int64_t)gridDim.x * blockDim.x) {
    int64_t e = i8 * 8;
    const float* src; unsigned short* dst;
    if (e < EMB_N) { src = emb + e;           dst = emb_b + e; }
    else           { src = wih + (e - EMB_N); dst = wih_b + (e - EMB_N); }
    float4 a = *reinterpret_cast<const float4*>(src);
    float4 b = *reinterpret_cast<const float4*>(src + 4);
    uint4 o;
    o.x = (unsigned)f2b(a.x) | ((unsigned)f2b(a.y) << 16);
    o.y = (unsigned)f2b(a.z) | ((unsigned)f2b(a.w) << 16);
    o.z = (unsigned)f2b(b.x) | ((unsigned)f2b(b.y) << 16);
    o.w = (unsigned)f2b(b.z) | ((unsigned)f2b(b.w) << 16);
    *reinterpret_cast<uint4*>(dst) = o;
  }
}

// ---------------- sequence lengths ----------------
__global__ void lengths_kernel(const int* __restrict__ x, int* __restrict__ len) {
  __shared__ int part[8];
  int b = blockIdx.x, tid = threadIdx.x;
  int v = (x[b * S_ + tid] != 0) ? 1 : 0;
  unsigned long long m = __ballot(v);
  if ((tid & 63) == 0) part[tid >> 6] = __popcll(m);
  __syncthreads();
  if (tid == 0) {
    int s = 0;
    #pragma unroll
    for (int i = 0; i < 8; ++i) s += part[i];
    len[b] = s;
  }
}

// -------- init exchange: parity0 = {tag 0 | h=0}, parity1 = {tag ~0} --------
__global__ void init_kernel(u64t* __restrict__ x64) {
  int i = blockIdx.x * blockDim.x + threadIdx.x;   // 128 x 256
  u64t v = (i < 16384) ? 0ull : 0xFFFFFFFF00000000ull;
  __hip_atomic_store(x64 + i, v, __ATOMIC_RELAXED, __HIP_MEMORY_SCOPE_AGENT);
}

// ---------------- phase 1: gi = emb[x] @ W_ih^T + b_ih (R5 layout) ----------
__global__ __launch_bounds__(256) void gi_kernel(
    const int* __restrict__ x, const unsigned short* __restrict__ emb_b,
    const unsigned short* __restrict__ wih_b, const float* __restrict__ b_ih,
    unsigned short* __restrict__ gi) {
  int tblk = blockIdx.x, g = blockIdx.y, w = blockIdx.z;
  int tid = threadIdx.x;
  int wv = tid >> 6, lane = tid & 63;
  int c16 = lane & 15, kq = lane >> 4;
  int t0 = tblk * 8 + wv, t1 = t0 + 4;

  int grow[6]; float bias[6];
  #pragma unroll
  for (int nt = 0; nt < 6; ++nt) {
    grow[nt] = (nt >> 1) * H_ + w * 32 + (nt & 1) * 16 + c16;
    bias[nt] = b_ih[grow[nt]];
  }
  int tok0 = x[(g * 16 + c16) * S_ + t0];
  int tok1 = x[(g * 16 + c16) * S_ + t1];

  f32x4 acc[2][6];
  #pragma unroll
  for (int nt = 0; nt < 6; ++nt) {
    acc[0][nt] = f32x4{bias[nt], bias[nt], bias[nt], bias[nt]};
    acc[1][nt] = acc[0][nt];
  }
  #pragma unroll
  for (int kk = 0; kk < 8; ++kk) {
    int kb = kk * 32 + kq * 8;
    bf16x8 A0 = ld_bf8(emb_b + (size_t)tok0 * E_ + kb);
    bf16x8 A1 = ld_bf8(emb_b + (size_t)tok1 * E_ + kb);
    #pragma unroll
    for (int nt = 0; nt < 6; ++nt) {
      bf16x8 Bf = ld_bf8(wih_b + (size_t)grow[nt] * E_ + kb);
      acc[0][nt] = __builtin_amdgcn_mfma_f32_16x16x32_bf16(A0, Bf, acc[0][nt], 0, 0, 0);
      acc[1][nt] = __builtin_amdgcn_mfma_f32_16x16x32_bf16(A1, Bf, acc[1][nt], 0, 0, 0);
    }
  }
  int wg = g * 16 + w;
  #pragma unroll
  for (int m = 0; m < 2; ++m) {
    int t = m ? t1 : t0;
    size_t base = ((size_t)(t * 64 + wg) * 16) * 96;
    #pragma unroll
    for (int nt = 0; nt < 6; ++nt)
      #pragma unroll
      for (int j = 0; j < 4; ++j)
        gi[base + (size_t)(kq * 4 + j) * 96 + nt * 16 + c16] = f2b(acc[m][nt][j]);
  }
}

// ---------------- phase 2: persistent GRU scan --------------------------------
// Tag-in-data protocol (R11, proven) with wave specialization:
//  - waves 0-1 (compute): each owns 16 gate-cols for ALL 3 gates over full
//    K=512 (3 interleaved 16-deep MFMA chains). D-layout co-locates r,z,n for
//    (batch,col) in one lane -> gates fully in-register, h_prev in registers,
//    no gh LDS round-trip, no second barrier.
//  - waves 2-9 (pollers): R11's exact proven poll idiom (asm dwordx4 batch ->
//    vmcnt(0) drain -> check; self-correcting against stale reads), 4 loads
//    per lane; after the single barrier they loop straight to polling t+1.
// One __syncthreads per step. Parity double-buffer; hazards: poller writes
// frag4[p^1] (t+1) while compute reads frag4[p] (t) - disjoint; poller's
// t+2 write to frag4[p] is after barrier t+1 which is after compute's reads.
__global__ __launch_bounds__(640, 1) void scan_kernel(
    const float* __restrict__ whh, const float* __restrict__ b_hh,
    const unsigned short* __restrict__ gi, const int* __restrict__ len,
    u64t* __restrict__ xchg64, float* __restrict__ out) {
  __shared__ uint4 frag4[2][1024];       // 32 KB: [(kk*4+kq)*16 + row]

  const int wgid = blockIdx.x, g = wgid >> 4, w = wgid & 15;
  const int tid = threadIdx.x, wv = tid >> 6, lane = tid & 63;
  const int c16 = lane & 15, kq = lane >> 4;

  // ---- compute waves 0-1: W_hh fragments (3 gates x 16 k-frags) + bias ----
  const int hc = w * 32 + (wv & 1) * 16 + c16;   // this lane's gate column
  bf16x8 Bf[3][16];
  float bias[3];
  float hreg[4] = {0.f, 0.f, 0.f, 0.f};
  int lenj[4];
  if (wv < 2) {
    #pragma unroll
    for (int pp = 0; pp < 3; ++pp) {
      int grow = pp * H_ + hc;
      bias[pp] = b_hh[grow];
      #pragma unroll
      for (int kk = 0; kk < 16; ++kk) {
        int kb = kk * 32 + kq * 8;
        const float* p = whh + (size_t)grow * H_ + kb;
        float4 a = *reinterpret_cast<const float4*>(p);
        float4 b = *reinterpret_cast<const float4*>(p + 4);
        uint4 v;
        v.x = (unsigned)f2b(a.x) | ((unsigned)f2b(a.y) << 16);
        v.y = (unsigned)f2b(a.z) | ((unsigned)f2b(a.w) << 16);
        v.z = (unsigned)f2b(b.x) | ((unsigned)f2b(b.y) << 16);
        v.w = (unsigned)f2b(b.z) | ((unsigned)f2b(b.w) << 16);
        Bf[pp][kk] = __builtin_bit_cast(bf16x8, v);
      }
    }
    #pragma unroll
    for (int j = 0; j < 4; ++j) lenj[j] = len[g * 16 + kq * 4 + j];
  }
  int tmax = 0;
  for (int bi = 0; bi < 16; ++bi) {
    int l = len[g * 16 + bi];
    tmax = l > tmax ? l : tmax;
  }

  // ---- poller geometry (waves 2-9): row = lane&15, run = (wv-2)*4+(lane>>4)
  const int prow = lane & 15;
  const int rn = (wv - 2) * 4 + (lane >> 4);   // 0..31, 8 u64 each
  const int fbase = rn * 2;
  __syncthreads();

  for (int t = 0; t < tmax; ++t) {
    const int p = t & 1;

    if (wv < 2) {
      // gi prefetch for this step (overlaps the pollers' spin)
      float gi_v[3][4];
      size_t base = ((size_t)(t * 64 + wgid) * 16) * 96;
      #pragma unroll
      for (int j = 0; j < 4; ++j) {
        size_t rowb = base + (size_t)(kq * 4 + j) * 96 + (wv & 1) * 16 + c16;
        gi_v[0][j] = b2f(gi[rowb]);
        gi_v[1][j] = b2f(gi[rowb + 32]);
        gi_v[2][j] = b2f(gi[rowb + 64]);
      }
      __syncthreads();   // frags for step t ready

      // MFMA: 3 gate chains x 16 k-frags, accumulate in-register
      f32x4 acc[3];
      #pragma unroll
      for (int pp = 0; pp < 3; ++pp)
        acc[pp] = f32x4{bias[pp], bias[pp], bias[pp], bias[pp]};
      #pragma unroll
      for (int kk = 0; kk < 16; ++kk) {
        uint4 af = frag4[p][(kk * 4 + kq) * 16 + c16];
        bf16x8 A = __builtin_bit_cast(bf16x8, af);
        acc[0] = __builtin_amdgcn_mfma_f32_16x16x32_bf16(A, Bf[0][kk], acc[0], 0, 0, 0);
        acc[1] = __builtin_amdgcn_mfma_f32_16x16x32_bf16(A, Bf[1][kk], acc[1], 0, 0, 0);
        acc[2] = __builtin_amdgcn_mfma_f32_16x16x32_bf16(A, Bf[2][kk], acc[2], 0, 0, 0);
      }
      // gates fully in-register; publish h(t+1) (store IS the signal)
      #pragma unroll
      for (int j = 0; j < 4; ++j) {
        float r = 1.0f / (1.0f + __expf(-(gi_v[0][j] + acc[0][j])));
        float z = 1.0f / (1.0f + __expf(-(gi_v[1][j] + acc[1][j])));
        float pre = gi_v[2][j] + r * acc[2][j];
        float e2 = __expf(2.0f * pre);
        float n = 1.0f - 2.0f / (e2 + 1.0f);
        float hn = z * (hreg[j] - n) + n;
        hreg[j] = hn;
        unsigned short hb = f2b(hn);
        unsigned nb = (unsigned)__shfl_down((int)hb, 1) & 0xFFFFu;
        if ((c16 & 1) == 0) {
          u64t pack = ((u64t)(uint32_t)(t + 1) << 32) | ((u64t)nb << 16) | hb;
          u64t* dst = xchg64 +
              (size_t)((((t + 1) & 1) * 4 + g) * 16 + kq * 4 + j) * 256 +
              (hc >> 1);
          __hip_atomic_store(dst, pack, __ATOMIC_RELAXED,
                             __HIP_MEMORY_SCOPE_AGENT);
        }
        if (t + 1 == lenj[j])
          out[(size_t)(g * 16 + kq * 4 + j) * H_ + hc] = hn;
      }
    } else {
      // ---- pollers: R11's proven batch-load/drain/check spin ----
      const char* pb = reinterpret_cast<const char*>(
          xchg64 + (size_t)((p * 4 + g) * 16 + prow) * 256 + rn * 8);
      const uint32_t etag = (uint32_t)t;
      uint4 L[4];
      bool ok = false;
      int s = 0;
      while (!ok && ++s < (1 << 16)) {
        #pragma unroll
        for (int i = 0; i < 4; ++i)
          asm volatile("global_load_dwordx4 %0, %1, off sc0 sc1"
                       : "=v"(L[i]) : "v"(pb + i * 16) : "memory");
        asm volatile("s_waitcnt vmcnt(0)" ::: "memory");
        ok = true;
        #pragma unroll
        for (int i = 0; i < 4; ++i)
          ok = ok & (L[i].y == etag) & (L[i].w == etag);
      }
      frag4[p][(fbase + 0) * 16 + prow] = uint4{L[0].x, L[0].z, L[1].x, L[1].z};
      frag4[p][(fbase + 1) * 16 + prow] = uint4{L[2].x, L[2].z, L[3].x, L[3].z};
      __syncthreads();   // frags for step t ready; loop to poll t+1 now
    }
  }
}

extern "C" void kernel_launch(void* const* d_in, const int* in_sizes, int n_in,
                              void* d_out, int out_size, void* d_ws, size_t ws_size,
                              hipStream_t stream) {
  const int*   x    = (const int*)d_in[0];
  const float* emb  = (const float*)d_in[1];
  const float* wih  = (const float*)d_in[2];
  const float* whh  = (const float*)d_in[3];
  const float* b_ih = (const float*)d_in[4];
  const float* b_hh = (const float*)d_in[5];
  float* out = (float*)d_out;

  char* ws = (char*)d_ws;
  const size_t GI_SZ    = (size_t)512 * 64 * 16 * 96 * 2;   // 100,663,296
  const size_t EMB_SZ   = (size_t)32000 * 256 * 2;          // 16,384,000
  const size_t WIH_SZ   = (size_t)1536 * 256 * 2;           //    786,432
  const size_t XCHG_SZ  = (size_t)32768 * 8;                //    262,144
  const size_t LEN_SZ   = 256;
  const size_t GI_OFF   = 0;
  const size_t EMB_OFF  = GI_OFF + GI_SZ;
  const size_t WIH_OFF  = EMB_OFF + EMB_SZ;
  const size_t XCHG_OFF = WIH_OFF + WIH_SZ;
  const size_t LEN_OFF  = XCHG_OFF + XCHG_SZ;
  if (ws_size < LEN_OFF + LEN_SZ) return;   // ~118 MB of scratch

  unsigned short* gi_p  = (unsigned short*)(ws + GI_OFF);
  unsigned short* emb_b = (unsigned short*)(ws + EMB_OFF);
  unsigned short* wih_b = (unsigned short*)(ws + WIH_OFF);
  u64t*           xchg  = (u64t*)(ws + XCHG_OFF);
  int*            len   = (int*)(ws + LEN_OFF);

  init_kernel<<<128, 256, 0, stream>>>(xchg);
  convert_kernel<<<2048, 256, 0, stream>>>(emb, wih, emb_b, wih_b);
  lengths_kernel<<<64, 512, 0, stream>>>(x, len);
  gi_kernel<<<dim3(64, 4, 16), 256, 0, stream>>>(x, emb_b, wih_b, b_ih, gi_p);
  scan_kernel<<<64, 640, 0, stream>>>(whh, b_hh, gi_p, len, xchg, out);
}

// Round 18
// 2959.159 us; speedup vs baseline: 4.3700x; 4.3700x over previous
//
#include <hip/hip_runtime.h>
#include <stdint.h>

#define B_  64
#define S_  512
#define E_  256
#define H_  512

typedef float  f32x4  __attribute__((ext_vector_type(4)));
typedef __bf16 bf16x8 __attribute__((ext_vector_type(8)));
typedef unsigned long long u64t;

__device__ __forceinline__ unsigned short f2b(float f) {
  uint32_t u = __builtin_bit_cast(uint32_t, f);
  uint32_t r = (u + 0x7FFFu + ((u >> 16) & 1u)) >> 16;
  return (unsigned short)r;
}
__device__ __forceinline__ float b2f(unsigned short s) {
  uint32_t u = ((uint32_t)s) << 16;
  return __builtin_bit_cast(float, u);
}
__device__ __forceinline__ bf16x8 ld_bf8(const unsigned short* p) {
  uint4 v = *reinterpret_cast<const uint4*>(p);
  return __builtin_bit_cast(bf16x8, v);
}

// ---------------- convert emb + W_ih to bf16 ----------------
__global__ void convert_kernel(const float* __restrict__ emb,
                               const float* __restrict__ wih,
                               unsigned short* __restrict__ emb_b,
                               unsigned short* __restrict__ wih_b) {
  const int64_t EMB_N = (int64_t)32000 * 256;
  const int64_t TOT8  = (EMB_N + (int64_t)1536 * 256) / 8;
  for (int64_t i8 = (int64_t)blockIdx.x * blockDim.x + threadIdx.x; i8 < TOT8;
       i8 += (int64_t)gridDim.x * blockDim.x) {
    int64_t e = i8 * 8;
    const float* src; unsigned short* dst;
    if (e < EMB_N) { src = emb + e;           dst = emb_b + e; }
    else           { src = wih + (e - EMB_N); dst = wih_b + (e - EMB_N); }
    float4 a = *reinterpret_cast<const float4*>(src);
    float4 b = *reinterpret_cast<const float4*>(src + 4);
    uint4 o;
    o.x = (unsigned)f2b(a.x) | ((unsigned)f2b(a.y) << 16);
    o.y = (unsigned)f2b(a.z) | ((unsigned)f2b(a.w) << 16);
    o.z = (unsigned)f2b(b.x) | ((unsigned)f2b(b.y) << 16);
    o.w = (unsigned)f2b(b.z) | ((unsigned)f2b(b.w) << 16);
    *reinterpret_cast<uint4*>(dst) = o;
  }
}

// ---------------- sequence lengths ----------------
__global__ void lengths_kernel(const int* __restrict__ x, int* __restrict__ len) {
  __shared__ int part[8];
  int b = blockIdx.x, tid = threadIdx.x;
  int v = (x[b * S_ + tid] != 0) ? 1 : 0;
  unsigned long long m = __ballot(v);
  if ((tid & 63) == 0) part[tid >> 6] = __popcll(m);
  __syncthreads();
  if (tid == 0) {
    int s = 0;
    #pragma unroll
    for (int i = 0; i < 8; ++i) s += part[i];
    len[b] = s;
  }
}

// -------- init exchange: parity0 = {tag 0 | h=0}, parity1 = {tag ~0} --------
// 2 parity x 4 groups x 16 rows x 256 u64 = 32768 u64; rewritten every launch.
__global__ void init_kernel(u64t* __restrict__ x64) {
  int i = blockIdx.x * blockDim.x + threadIdx.x;   // 128 x 256
  u64t v = (i < 16384) ? 0ull : 0xFFFFFFFF00000000ull;
  __hip_atomic_store(x64 + i, v, __ATOMIC_RELAXED, __HIP_MEMORY_SCOPE_AGENT);
}

// ---------------- phase 1: gi = emb[x] @ W_ih^T + b_ih (R5 layout) ----------
__global__ __launch_bounds__(256) void gi_kernel(
    const int* __restrict__ x, const unsigned short* __restrict__ emb_b,
    const unsigned short* __restrict__ wih_b, const float* __restrict__ b_ih,
    unsigned short* __restrict__ gi) {
  int tblk = blockIdx.x, g = blockIdx.y, w = blockIdx.z;
  int tid = threadIdx.x;
  int wv = tid >> 6, lane = tid & 63;
  int c16 = lane & 15, kq = lane >> 4;
  int t0 = tblk * 8 + wv, t1 = t0 + 4;

  int grow[6]; float bias[6];
  #pragma unroll
  for (int nt = 0; nt < 6; ++nt) {
    grow[nt] = (nt >> 1) * H_ + w * 32 + (nt & 1) * 16 + c16;
    bias[nt] = b_ih[grow[nt]];
  }
  int tok0 = x[(g * 16 + c16) * S_ + t0];
  int tok1 = x[(g * 16 + c16) * S_ + t1];

  f32x4 acc[2][6];
  #pragma unroll
  for (int nt = 0; nt < 6; ++nt) {
    acc[0][nt] = f32x4{bias[nt], bias[nt], bias[nt], bias[nt]};
    acc[1][nt] = acc[0][nt];
  }
  #pragma unroll
  for (int kk = 0; kk < 8; ++kk) {
    int kb = kk * 32 + kq * 8;
    bf16x8 A0 = ld_bf8(emb_b + (size_t)tok0 * E_ + kb);
    bf16x8 A1 = ld_bf8(emb_b + (size_t)tok1 * E_ + kb);
    #pragma unroll
    for (int nt = 0; nt < 6; ++nt) {
      bf16x8 Bf = ld_bf8(wih_b + (size_t)grow[nt] * E_ + kb);
      acc[0][nt] = __builtin_amdgcn_mfma_f32_16x16x32_bf16(A0, Bf, acc[0][nt], 0, 0, 0);
      acc[1][nt] = __builtin_amdgcn_mfma_f32_16x16x32_bf16(A1, Bf, acc[1][nt], 0, 0, 0);
    }
  }
  int wg = g * 16 + w;
  #pragma unroll
  for (int m = 0; m < 2; ++m) {
    int t = m ? t1 : t0;
    size_t base = ((size_t)(t * 64 + wg) * 16) * 96;
    #pragma unroll
    for (int nt = 0; nt < 6; ++nt)
      #pragma unroll
      for (int j = 0; j < 4; ++j)
        gi[base + (size_t)(kq * 4 + j) * 96 + nt * 16 + c16] = f2b(acc[m][nt][j]);
  }
}

// ---------------- phase 2: persistent GRU scan --------------------------------
// Tag-in-data protocol (R8, proven) + designated pollers + LDS broadcast:
// waves 0-3 poll the group's 32KB u64 tile {tag32|2xbf16} via sc0 sc1 16B
// loads (16 u64/lane), write payloads into a fragment-ordered LDS tile,
// barrier; all 12 waves ds_read_b128 A-frags from LDS; gates in 8 waves;
// producers store u64 {t+1|h pair} — the store IS the signal (no drain, no
// flag, no trailing barrier). Parity double buffer; poll grounds at init
// tag 0; bounded spin keeps any failure finite.
__global__ __launch_bounds__(768, 1) void scan_kernel(
    const float* __restrict__ whh, const float* __restrict__ b_hh,
    const unsigned short* __restrict__ gi, const int* __restrict__ len,
    u64t* __restrict__ xchg64, float* __restrict__ out) {
  __shared__ float gh[2][16 * 100];      // 12.8 KB
  __shared__ float hown[16 * 32];        //  2 KB
  __shared__ uint4 frag4[2][1024];       // 32 KB: [parity][((kh*8+kk)*4+kq)*16 + row]

  const int wgid = blockIdx.x, g = wgid >> 4, w = wgid & 15;
  const int tid = threadIdx.x, wv = tid >> 6, lane = tid & 63;
  const int nt = wv % 6, kh = wv / 6;    // 12 waves: 6 n-tiles x 2 K-halves
  const int c16 = lane & 15, kq = lane >> 4;

  // loop-invariant W_hh B-fragments in registers (bf16)
  const int grow = (nt >> 1) * H_ + w * 32 + (nt & 1) * 16 + c16;
  bf16x8 Bf[8];
  #pragma unroll
  for (int kk = 0; kk < 8; ++kk) {
    int kb = kh * 256 + kk * 32 + kq * 8;
    const float* p = whh + (size_t)grow * H_ + kb;
    float4 a = *reinterpret_cast<const float4*>(p);
    float4 b = *reinterpret_cast<const float4*>(p + 4);
    uint4 v;
    v.x = (unsigned)f2b(a.x) | ((unsigned)f2b(a.y) << 16);
    v.y = (unsigned)f2b(a.z) | ((unsigned)f2b(a.w) << 16);
    v.z = (unsigned)f2b(b.x) | ((unsigned)f2b(b.y) << 16);
    v.w = (unsigned)f2b(b.z) | ((unsigned)f2b(b.w) << 16);
    Bf[kk] = __builtin_bit_cast(bf16x8, v);
  }
  const float bhh_v = (kh == 0) ? b_hh[grow] : 0.0f;

  if (tid < 512) hown[tid] = 0.0f;
  const int i_e = (tid >> 5) & 15, c_e = tid & 31;
  const int lenv = len[g * 16 + i_e];
  int tmax = 0;
  for (int bi = 0; bi < 16; ++bi) {
    int l = len[g * 16 + bi];
    tmax = l > tmax ? l : tmax;
  }

  // poller geometry (waves 0-3): row = lane&15, colrun = wv*4 + (lane>>4)
  const int prow = lane & 15, pcolrun = wv * 4 + (lane >> 4);
  const int pkh = pcolrun >> 3, pkk = pcolrun & 7;
  __syncthreads();

  for (int t = 0; t < tmax; ++t) {
    const int p = t & 1;
    // gi prefetch (plain cached loads; overlap with the poll)
    size_t gib = ((size_t)(t * 64 + wgid) * 16 + i_e) * 96;
    float i_r = b2f(gi[gib + c_e]);
    float i_z = b2f(gi[gib + 32 + c_e]);
    float i_n = b2f(gi[gib + 64 + c_e]);

    // ---- phase A: waves 0-3 poll h(t) and broadcast to LDS frag tile ----
    if (wv < 4) {
      const char* pb = reinterpret_cast<const char*>(
          xchg64 + (size_t)((p * 4 + g) * 16 + prow) * 256 + pcolrun * 16);
      const uint32_t etag = (uint32_t)t;
      uint4 L[8];
      bool ok = false;
      int s = 0;
      while (!ok && ++s < (1 << 16)) {
        #pragma unroll
        for (int i = 0; i < 8; ++i)
          asm volatile("global_load_dwordx4 %0, %1, off sc0 sc1"
                       : "=v"(L[i]) : "v"(pb + i * 16) : "memory");
        asm volatile("s_waitcnt vmcnt(0)" ::: "memory");
        ok = true;
        #pragma unroll
        for (int i = 0; i < 8; ++i)
          ok = ok & (L[i].y == etag) & (L[i].w == etag);
      }
      #pragma unroll
      for (int q = 0; q < 4; ++q)
        frag4[p][((pkh * 8 + pkk) * 4 + q) * 16 + prow] =
            uint4{L[2 * q].x, L[2 * q].z, L[2 * q + 1].x, L[2 * q + 1].z};
    }
    __syncthreads();

    // ---- phase B: MFMA from LDS fragments ----
    f32x4 acc = f32x4{bhh_v, bhh_v, bhh_v, bhh_v};
    #pragma unroll
    for (int kk = 0; kk < 8; ++kk) {
      uint4 af = frag4[p][((kh * 8 + kk) * 4 + kq) * 16 + c16];
      acc = __builtin_amdgcn_mfma_f32_16x16x32_bf16(
          __builtin_bit_cast(bf16x8, af), Bf[kk], acc, 0, 0, 0);
    }
    float* ghp = gh[kh];
    #pragma unroll
    for (int j = 0; j < 4; ++j)
      ghp[(kq * 4 + j) * 100 + nt * 16 + c16] = acc[j];
    __syncthreads();

    // ---- phase C: gates + publish h(t+1) (store IS the signal) ----
    if (tid < 512) {
      float gr_ = gh[0][i_e * 100 + c_e]      + gh[1][i_e * 100 + c_e];
      float gz_ = gh[0][i_e * 100 + 32 + c_e] + gh[1][i_e * 100 + 32 + c_e];
      float gn_ = gh[0][i_e * 100 + 64 + c_e] + gh[1][i_e * 100 + 64 + c_e];
      float hp = hown[i_e * 32 + c_e];
      float r = 1.0f / (1.0f + __expf(-(i_r + gr_)));
      float z = 1.0f / (1.0f + __expf(-(i_z + gz_)));
      float pre = i_n + r * gn_;
      float e2 = __expf(2.0f * pre);
      float n = 1.0f - 2.0f / (e2 + 1.0f);
      float hn = z * (hp - n) + n;
      hown[i_e * 32 + c_e] = hn;
      unsigned short hb = f2b(hn);
      unsigned nb = (unsigned)__shfl_down((int)hb, 1) & 0xFFFFu;
      if ((c_e & 1) == 0) {
        u64t pack = ((u64t)(uint32_t)(t + 1) << 32) | ((u64t)nb << 16) | hb;
        u64t* dst = xchg64 + (size_t)((((t + 1) & 1) * 4 + g) * 16 + i_e) * 256 +
                    w * 16 + (c_e >> 1);
        __hip_atomic_store(dst, pack, __ATOMIC_RELAXED,
                           __HIP_MEMORY_SCOPE_AGENT);
      }
      if (t + 1 == lenv) out[(size_t)(g * 16 + i_e) * H_ + w * 32 + c_e] = hn;
    }
    // no trailing barrier: next step's poll (parity-flipped buffers) is the
    // transitive proof that every peer and our own gate waves finished.
  }
}

extern "C" void kernel_launch(void* const* d_in, const int* in_sizes, int n_in,
                              void* d_out, int out_size, void* d_ws, size_t ws_size,
                              hipStream_t stream) {
  const int*   x    = (const int*)d_in[0];
  const float* emb  = (const float*)d_in[1];
  const float* wih  = (const float*)d_in[2];
  const float* whh  = (const float*)d_in[3];
  const float* b_ih = (const float*)d_in[4];
  const float* b_hh = (const float*)d_in[5];
  float* out = (float*)d_out;

  char* ws = (char*)d_ws;
  const size_t GI_SZ    = (size_t)512 * 64 * 16 * 96 * 2;   // 100,663,296
  const size_t EMB_SZ   = (size_t)32000 * 256 * 2;          // 16,384,000
  const size_t WIH_SZ   = (size_t)1536 * 256 * 2;           //    786,432
  const size_t XCHG_SZ  = (size_t)32768 * 8;                //    262,144
  const size_t LEN_SZ   = 256;
  const size_t GI_OFF   = 0;
  const size_t EMB_OFF  = GI_OFF + GI_SZ;
  const size_t WIH_OFF  = EMB_OFF + EMB_SZ;
  const size_t XCHG_OFF = WIH_OFF + WIH_SZ;
  const size_t LEN_OFF  = XCHG_OFF + XCHG_SZ;
  if (ws_size < LEN_OFF + LEN_SZ) return;   // ~118 MB of scratch

  unsigned short* gi_p  = (unsigned short*)(ws + GI_OFF);
  unsigned short* emb_b = (unsigned short*)(ws + EMB_OFF);
  unsigned short* wih_b = (unsigned short*)(ws + WIH_OFF);
  u64t*           xchg  = (u64t*)(ws + XCHG_OFF);
  int*            len   = (int*)(ws + LEN_OFF);

  init_kernel<<<128, 256, 0, stream>>>(xchg);
  convert_kernel<<<2048, 256, 0, stream>>>(emb, wih, emb_b, wih_b);
  lengths_kernel<<<64, 512, 0, stream>>>(x, len);
  gi_kernel<<<dim3(64, 4, 16), 256, 0, stream>>>(x, emb_b, wih_b, b_ih, gi_p);
  scan_kernel<<<64, 768, 0, stream>>>(whh, b_hh, gi_p, len, xchg, out);
}

// Round 19
// 2794.853 us; speedup vs baseline: 4.6269x; 1.0588x over previous
//
#include <hip/hip_runtime.h>
#include <stdint.h>

#define B_  64
#define S_  512
#define E_  256
#define H_  512

typedef float  f32x4  __attribute__((ext_vector_type(4)));
typedef __bf16 bf16x8 __attribute__((ext_vector_type(8)));
typedef unsigned long long u64t;

__device__ __forceinline__ unsigned short f2b(float f) {
  uint32_t u = __builtin_bit_cast(uint32_t, f);
  uint32_t r = (u + 0x7FFFu + ((u >> 16) & 1u)) >> 16;
  return (unsigned short)r;
}
__device__ __forceinline__ float b2f(unsigned short s) {
  uint32_t u = ((uint32_t)s) << 16;
  return __builtin_bit_cast(float, u);
}
__device__ __forceinline__ bf16x8 ld_bf8(const unsigned short* p) {
  uint4 v = *reinterpret_cast<const uint4*>(p);
  return __builtin_bit_cast(bf16x8, v);
}

// ---------------- convert emb + W_ih to bf16 ----------------
__global__ void convert_kernel(const float* __restrict__ emb,
                               const float* __restrict__ wih,
                               unsigned short* __restrict__ emb_b,
                               unsigned short* __restrict__ wih_b) {
  const int64_t EMB_N = (int64_t)32000 * 256;
  const int64_t TOT8  = (EMB_N + (int64_t)1536 * 256) / 8;
  for (int64_t i8 = (int64_t)blockIdx.x * blockDim.x + threadIdx.x; i8 < TOT8;
       i8 += (int64_t)gridDim.x * blockDim.x) {
    int64_t e = i8 * 8;
    const float* src; unsigned short* dst;
    if (e < EMB_N) { src = emb + e;           dst = emb_b + e; }
    else           { src = wih + (e - EMB_N); dst = wih_b + (e - EMB_N); }
    float4 a = *reinterpret_cast<const float4*>(src);
    float4 b = *reinterpret_cast<const float4*>(src + 4);
    uint4 o;
    o.x = (unsigned)f2b(a.x) | ((unsigned)f2b(a.y) << 16);
    o.y = (unsigned)f2b(a.z) | ((unsigned)f2b(a.w) << 16);
    o.z = (unsigned)f2b(b.x) | ((unsigned)f2b(b.y) << 16);
    o.w = (unsigned)f2b(b.z) | ((unsigned)f2b(b.w) << 16);
    *reinterpret_cast<uint4*>(dst) = o;
  }
}

// ---------------- sequence lengths ----------------
__global__ void lengths_kernel(const int* __restrict__ x, int* __restrict__ len) {
  __shared__ int part[8];
  int b = blockIdx.x, tid = threadIdx.x;
  int v = (x[b * S_ + tid] != 0) ? 1 : 0;
  unsigned long long m = __ballot(v);
  if ((tid & 63) == 0) part[tid >> 6] = __popcll(m);
  __syncthreads();
  if (tid == 0) {
    int s = 0;
    #pragma unroll
    for (int i = 0; i < 8; ++i) s += part[i];
    len[b] = s;
  }
}

// -------- init exchange: parity0 = {tag 0 | h=0}, parity1 = {tag ~0} --------
__global__ void init_kernel(u64t* __restrict__ x64) {
  int i = blockIdx.x * blockDim.x + threadIdx.x;   // 128 x 256
  u64t v = (i < 16384) ? 0ull : 0xFFFFFFFF00000000ull;
  __hip_atomic_store(x64 + i, v, __ATOMIC_RELAXED, __HIP_MEMORY_SCOPE_AGENT);
}

// ---------------- phase 1: gi = emb[x] @ W_ih^T + b_ih (R5 layout) ----------
__global__ __launch_bounds__(256) void gi_kernel(
    const int* __restrict__ x, const unsigned short* __restrict__ emb_b,
    const unsigned short* __restrict__ wih_b, const float* __restrict__ b_ih,
    unsigned short* __restrict__ gi) {
  int tblk = blockIdx.x, g = blockIdx.y, w = blockIdx.z;
  int tid = threadIdx.x;
  int wv = tid >> 6, lane = tid & 63;
  int c16 = lane & 15, kq = lane >> 4;
  int t0 = tblk * 8 + wv, t1 = t0 + 4;

  int grow[6]; float bias[6];
  #pragma unroll
  for (int nt = 0; nt < 6; ++nt) {
    grow[nt] = (nt >> 1) * H_ + w * 32 + (nt & 1) * 16 + c16;
    bias[nt] = b_ih[grow[nt]];
  }
  int tok0 = x[(g * 16 + c16) * S_ + t0];
  int tok1 = x[(g * 16 + c16) * S_ + t1];

  f32x4 acc[2][6];
  #pragma unroll
  for (int nt = 0; nt < 6; ++nt) {
    acc[0][nt] = f32x4{bias[nt], bias[nt], bias[nt], bias[nt]};
    acc[1][nt] = acc[0][nt];
  }
  #pragma unroll
  for (int kk = 0; kk < 8; ++kk) {
    int kb = kk * 32 + kq * 8;
    bf16x8 A0 = ld_bf8(emb_b + (size_t)tok0 * E_ + kb);
    bf16x8 A1 = ld_bf8(emb_b + (size_t)tok1 * E_ + kb);
    #pragma unroll
    for (int nt = 0; nt < 6; ++nt) {
      bf16x8 Bf = ld_bf8(wih_b + (size_t)grow[nt] * E_ + kb);
      acc[0][nt] = __builtin_amdgcn_mfma_f32_16x16x32_bf16(A0, Bf, acc[0][nt], 0, 0, 0);
      acc[1][nt] = __builtin_amdgcn_mfma_f32_16x16x32_bf16(A1, Bf, acc[1][nt], 0, 0, 0);
    }
  }
  int wg = g * 16 + w;
  #pragma unroll
  for (int m = 0; m < 2; ++m) {
    int t = m ? t1 : t0;
    size_t base = ((size_t)(t * 64 + wg) * 16) * 96;
    #pragma unroll
    for (int nt = 0; nt < 6; ++nt)
      #pragma unroll
      for (int j = 0; j < 4; ++j)
        gi[base + (size_t)(kq * 4 + j) * 96 + nt * 16 + c16] = f2b(acc[m][nt][j]);
  }
}

// ---------------- phase 2: persistent GRU scan --------------------------------
// R11 (tag-in-data + designated pollers + LDS broadcast) with ONE change:
// pollers are waves 8-11 (which skip phase C) instead of waves 0-3. After
// barrier(B,t) they immediately start polling step t+1, spinning through the
// producers' phase C — when the last h-store commits, a poll sweep is already
// mid-flight, so detection costs ~half a poll period instead of issue+RT
// after phase C. Barrier count stays uniform (2/step, all waves). Hazard:
// poller writes frag4[(t+1)&1] between barrier(B,t) and barrier(A,t+1);
// compute reads it only after barrier(A,t+1) — disjoint by parity+barrier.
__global__ __launch_bounds__(768, 1) void scan_kernel(
    const float* __restrict__ whh, const float* __restrict__ b_hh,
    const unsigned short* __restrict__ gi, const int* __restrict__ len,
    u64t* __restrict__ xchg64, float* __restrict__ out) {
  __shared__ float gh[2][16 * 100];      // 12.8 KB
  __shared__ float hown[16 * 32];        //  2 KB
  __shared__ uint4 frag4[2][1024];       // 32 KB

  const int wgid = blockIdx.x, g = wgid >> 4, w = wgid & 15;
  const int tid = threadIdx.x, wv = tid >> 6, lane = tid & 63;
  const int nt = wv % 6, kh = wv / 6;    // 12 waves: 6 n-tiles x 2 K-halves
  const int c16 = lane & 15, kq = lane >> 4;

  // loop-invariant W_hh B-fragments in registers (bf16)
  const int grow = (nt >> 1) * H_ + w * 32 + (nt & 1) * 16 + c16;
  bf16x8 Bf[8];
  #pragma unroll
  for (int kk = 0; kk < 8; ++kk) {
    int kb = kh * 256 + kk * 32 + kq * 8;
    const float* p = whh + (size_t)grow * H_ + kb;
    float4 a = *reinterpret_cast<const float4*>(p);
    float4 b = *reinterpret_cast<const float4*>(p + 4);
    uint4 v;
    v.x = (unsigned)f2b(a.x) | ((unsigned)f2b(a.y) << 16);
    v.y = (unsigned)f2b(a.z) | ((unsigned)f2b(a.w) << 16);
    v.z = (unsigned)f2b(b.x) | ((unsigned)f2b(b.y) << 16);
    v.w = (unsigned)f2b(b.z) | ((unsigned)f2b(b.w) << 16);
    Bf[kk] = __builtin_bit_cast(bf16x8, v);
  }
  const float bhh_v = (kh == 0) ? b_hh[grow] : 0.0f;

  if (tid < 512) hown[tid] = 0.0f;
  const int i_e = (tid >> 5) & 15, c_e = tid & 31;
  const int lenv = len[g * 16 + i_e];
  int tmax = 0;
  for (int bi = 0; bi < 16; ++bi) {
    int l = len[g * 16 + bi];
    tmax = l > tmax ? l : tmax;
  }

  // poller geometry (waves 8-11): row = lane&15, colrun = (wv-8)*4+(lane>>4)
  const int prow = lane & 15, pcolrun = (wv - 8) * 4 + (lane >> 4);
  const int pkh = pcolrun >> 3, pkk = pcolrun & 7;
  __syncthreads();

  for (int t = 0; t < tmax; ++t) {
    const int p = t & 1;
    // gi prefetch — only gate waves (0-7) need it; overlaps the poll
    float i_r = 0.f, i_z = 0.f, i_n = 0.f;
    if (tid < 512) {
      size_t gib = ((size_t)(t * 64 + wgid) * 16 + i_e) * 96;
      i_r = b2f(gi[gib + c_e]);
      i_z = b2f(gi[gib + 32 + c_e]);
      i_n = b2f(gi[gib + 64 + c_e]);
    }

    // ---- phase A: waves 8-11 poll h(t) and broadcast to LDS frag tile ----
    if (wv >= 8) {
      const char* pb = reinterpret_cast<const char*>(
          xchg64 + (size_t)((p * 4 + g) * 16 + prow) * 256 + pcolrun * 16);
      const uint32_t etag = (uint32_t)t;
      uint4 L[8];
      bool ok = false;
      int s = 0;
      while (!ok && ++s < (1 << 16)) {
        #pragma unroll
        for (int i = 0; i < 8; ++i)
          asm volatile("global_load_dwordx4 %0, %1, off sc0 sc1"
                       : "=v"(L[i]) : "v"(pb + i * 16) : "memory");
        asm volatile("s_waitcnt vmcnt(0)" ::: "memory");
        ok = true;
        #pragma unroll
        for (int i = 0; i < 8; ++i)
          ok = ok & (L[i].y == etag) & (L[i].w == etag);
      }
      #pragma unroll
      for (int q = 0; q < 4; ++q)
        frag4[p][((pkh * 8 + pkk) * 4 + q) * 16 + prow] =
            uint4{L[2 * q].x, L[2 * q].z, L[2 * q + 1].x, L[2 * q + 1].z};
    }
    __syncthreads();

    // ---- phase B: MFMA from LDS fragments (all 12 waves) ----
    f32x4 acc = f32x4{bhh_v, bhh_v, bhh_v, bhh_v};
    #pragma unroll
    for (int kk = 0; kk < 8; ++kk) {
      uint4 af = frag4[p][((kh * 8 + kk) * 4 + kq) * 16 + c16];
      acc = __builtin_amdgcn_mfma_f32_16x16x32_bf16(
          __builtin_bit_cast(bf16x8, af), Bf[kk], acc, 0, 0, 0);
    }
    float* ghp = gh[kh];
    #pragma unroll
    for (int j = 0; j < 4; ++j)
      ghp[(kq * 4 + j) * 100 + nt * 16 + c16] = acc[j];
    __syncthreads();

    // ---- phase C: gate waves 0-7 compute gates + publish h(t+1) ----
    // poller waves 8-11 skip this and immediately poll step t+1.
    if (tid < 512) {
      float gr_ = gh[0][i_e * 100 + c_e]      + gh[1][i_e * 100 + c_e];
      float gz_ = gh[0][i_e * 100 + 32 + c_e] + gh[1][i_e * 100 + 32 + c_e];
      float gn_ = gh[0][i_e * 100 + 64 + c_e] + gh[1][i_e * 100 + 64 + c_e];
      float hp = hown[i_e * 32 + c_e];
      float r = 1.0f / (1.0f + __expf(-(i_r + gr_)));
      float z = 1.0f / (1.0f + __expf(-(i_z + gz_)));
      float pre = i_n + r * gn_;
      float e2 = __expf(2.0f * pre);
      float n = 1.0f - 2.0f / (e2 + 1.0f);
      float hn = z * (hp - n) + n;
      hown[i_e * 32 + c_e] = hn;
      unsigned short hb = f2b(hn);
      unsigned nb = (unsigned)__shfl_down((int)hb, 1) & 0xFFFFu;
      if ((c_e & 1) == 0) {
        u64t pack = ((u64t)(uint32_t)(t + 1) << 32) | ((u64t)nb << 16) | hb;
        u64t* dst = xchg64 + (size_t)((((t + 1) & 1) * 4 + g) * 16 + i_e) * 256 +
                    w * 16 + (c_e >> 1);
        __hip_atomic_store(dst, pack, __ATOMIC_RELAXED,
                           __HIP_MEMORY_SCOPE_AGENT);
      }
      if (t + 1 == lenv) out[(size_t)(g * 16 + i_e) * H_ + w * 32 + c_e] = hn;
    }
    // no trailing barrier: next step's poll is the transitive completion proof
  }
}

extern "C" void kernel_launch(void* const* d_in, const int* in_sizes, int n_in,
                              void* d_out, int out_size, void* d_ws, size_t ws_size,
                              hipStream_t stream) {
  const int*   x    = (const int*)d_in[0];
  const float* emb  = (const float*)d_in[1];
  const float* wih  = (const float*)d_in[2];
  const float* whh  = (const float*)d_in[3];
  const float* b_ih = (const float*)d_in[4];
  const float* b_hh = (const float*)d_in[5];
  float* out = (float*)d_out;

  char* ws = (char*)d_ws;
  const size_t GI_SZ    = (size_t)512 * 64 * 16 * 96 * 2;   // 100,663,296
  const size_t EMB_SZ   = (size_t)32000 * 256 * 2;          // 16,384,000
  const size_t WIH_SZ   = (size_t)1536 * 256 * 2;           //    786,432
  const size_t XCHG_SZ  = (size_t)32768 * 8;                //    262,144
  const size_t LEN_SZ   = 256;
  const size_t GI_OFF   = 0;
  const size_t EMB_OFF  = GI_OFF + GI_SZ;
  const size_t WIH_OFF  = EMB_OFF + EMB_SZ;
  const size_t XCHG_OFF = WIH_OFF + WIH_SZ;
  const size_t LEN_OFF  = XCHG_OFF + XCHG_SZ;
  if (ws_size < LEN_OFF + LEN_SZ) return;   // ~118 MB of scratch

  unsigned short* gi_p  = (unsigned short*)(ws + GI_OFF);
  unsigned short* emb_b = (unsigned short*)(ws + EMB_OFF);
  unsigned short* wih_b = (unsigned short*)(ws + WIH_OFF);
  u64t*           xchg  = (u64t*)(ws + XCHG_OFF);
  int*            len   = (int*)(ws + LEN_OFF);

  init_kernel<<<128, 256, 0, stream>>>(xchg);
  convert_kernel<<<2048, 256, 0, stream>>>(emb, wih, emb_b, wih_b);
  lengths_kernel<<<64, 512, 0, stream>>>(x, len);
  gi_kernel<<<dim3(64, 4, 16), 256, 0, stream>>>(x, emb_b, wih_b, b_ih, gi_p);
  scan_kernel<<<64, 768, 0, stream>>>(whh, b_hh, gi_p, len, xchg, out);
}